// Round 1
// baseline (2945.457 us; speedup 1.0000x reference)
//
#include <hip/hip_runtime.h>
#include <math.h>

// NeuromorphicPrivacyNetwork: 3-layer LIF SNN, T=16, B=256, sizes 1024->2048->1024->512.
// Strategy:
//   - hoist layer-0 GEMM (inputs @ w0^T) out of the time loop (input constant per step)
//   - layers 1/2: spikes are binary -> per-batch-row block, wave-uniform spike bitmask,
//     scalar-branch sparse accumulation of transposed-weight rows (coalesced adds)
//   - cost/entropy accumulated online (trailing-window weight = min(10, T-s) per step)

#define B 256
#define T_STEPS 16

// ---------------- helpers ----------------

__device__ inline void cost_accum(float csum, int cnt, float* cost, float* tot, int t) {
  #pragma unroll
  for (int off = 32; off > 0; off >>= 1) {
    csum += __shfl_down(csum, off);
    cnt  += __shfl_down(cnt, off);
  }
  __shared__ float sc[4];
  __shared__ int   si[4];
  int wid = threadIdx.x >> 6;
  if ((threadIdx.x & 63) == 0) { sc[wid] = csum; si[wid] = cnt; }
  __syncthreads();
  if (threadIdx.x == 0) {
    float c = sc[0] + sc[1] + sc[2] + sc[3];
    int   k = si[0] + si[1] + si[2] + si[3];
    int s = t - 1;
    int f = T_STEPS - s; if (f > 10) f = 10;
    // per-spike cost: SYN_EPS * fac/10 * wn = 0.1 * fac/10 * wn = 0.01*fac*wn
    atomicAdd(cost, c * (0.01f * (float)f));
    atomicAdd(tot, (float)k);
  }
}

// ---------------- init ----------------

__global__ __launch_bounds__(256) void init_kernel(float* __restrict__ V,
                                                   float* __restrict__ LS,
                                                   float* __restrict__ cost,
                                                   float* __restrict__ tot) {
  int idx = blockIdx.x * 256 + threadIdx.x;  // grid covers 917504 exactly
  V[idx]  = 0.f;
  LS[idx] = -1e9f;
  if (idx == 0) { *cost = 0.f; *tot = 0.f; }
}

// ---------------- weight row norms ----------------

__global__ __launch_bounds__(64) void wnorm_kernel(const float* __restrict__ w0,
                                                   const float* __restrict__ w1,
                                                   const float* __restrict__ w2,
                                                   float* __restrict__ wn) {
  int r = blockIdx.x;  // 0..3583
  const float* row; int K;
  if (r < 2048)      { row = w0 + (size_t)r * 1024;          K = 1024; }
  else if (r < 3072) { row = w1 + (size_t)(r - 2048) * 2048; K = 2048; }
  else               { row = w2 + (size_t)(r - 3072) * 1024; K = 1024; }
  float ss = 0.f;
  for (int k = threadIdx.x; k < K; k += 64) { float x = row[k]; ss += x * x; }
  #pragma unroll
  for (int off = 32; off > 0; off >>= 1) ss += __shfl_down(ss, off);
  if (threadIdx.x == 0) wn[r] = sqrtf(ss);
}

// ---------------- transpose (w [rows][cols] -> wT [cols][rows]) ----------------

__global__ __launch_bounds__(256) void transpose_kernel(const float* __restrict__ src,
                                                        float* __restrict__ dst,
                                                        int rows, int cols) {
  __shared__ float tile[32][33];
  int tx = threadIdx.x & 31, ty = threadIdx.x >> 5;  // 32 x 8
  int c0 = blockIdx.x * 32, r0 = blockIdx.y * 32;
  #pragma unroll
  for (int j = 0; j < 32; j += 8)
    tile[ty + j][tx] = src[(size_t)(r0 + ty + j) * cols + c0 + tx];
  __syncthreads();
  #pragma unroll
  for (int j = 0; j < 32; j += 8)
    dst[(size_t)(c0 + ty + j) * rows + r0 + tx] = tile[tx][ty + j];
}

// ---------------- base0 = inputs @ w0^T  [256 x 2048] ----------------

__global__ __launch_bounds__(256) void base0_kernel(const float* __restrict__ A,   // [256][1024]
                                                    const float* __restrict__ W,   // [2048][1024]
                                                    float* __restrict__ C) {       // [256][2048]
  __shared__ float As[64][36];
  __shared__ float Ws[64][36];
  const int b0 = blockIdx.x * 64;
  const int n0 = blockIdx.y * 64;
  const int tid = threadIdx.x;
  const int tn = tid & 15, tb = tid >> 4;
  float acc[4][4] = {};
  for (int k0 = 0; k0 < 1024; k0 += 32) {
    __syncthreads();
    #pragma unroll
    for (int i = 0; i < 8; ++i) {
      int e = tid + i * 256;
      int r = e >> 5, c = e & 31;
      As[r][c] = A[(size_t)(b0 + r) * 1024 + k0 + c];
      Ws[r][c] = W[(size_t)(n0 + r) * 1024 + k0 + c];
    }
    __syncthreads();
    #pragma unroll
    for (int kk = 0; kk < 32; ++kk) {
      float a[4], w[4];
      #pragma unroll
      for (int i = 0; i < 4; ++i) a[i] = As[tb * 4 + i][kk];
      #pragma unroll
      for (int i = 0; i < 4; ++i) w[i] = Ws[tn * 4 + i][kk];
      #pragma unroll
      for (int i = 0; i < 4; ++i)
        #pragma unroll
        for (int j = 0; j < 4; ++j)
          acc[i][j] += a[i] * w[j];
    }
  }
  #pragma unroll
  for (int i = 0; i < 4; ++i)
    #pragma unroll
    for (int j = 0; j < 4; ++j)
      C[(size_t)(b0 + tb * 4 + i) * 2048 + n0 + tn * 4 + j] = acc[i][j];
}

// ---------------- layer 0 per-step LIF (elementwise, uses hoisted base0) ----------------

__global__ __launch_bounds__(256) void lif0_kernel(const float* __restrict__ base0,
                                                   const float* __restrict__ cn0,
                                                   const float* __restrict__ tn0,
                                                   const float* __restrict__ th0,
                                                   const float* __restrict__ wn,
                                                   float* __restrict__ V,
                                                   float* __restrict__ ls,
                                                   unsigned long long* __restrict__ bits,
                                                   float* cost, float* tot, int t) {
  int idx = blockIdx.x * 256 + threadIdx.x;  // 256*2048 total
  int n = idx & 2047;
  int toff = (t - 1) * (B * 2048) + idx;
  float wnn = wn[n];
  float cur = base0[idx] + cn0[toff] * (0.05f * wnn);
  float v = V[idx], l = ls[idx];
  float tf = (float)t;
  bool refrac = (tf - l) < 2.0f;
  float Vn = refrac ? v : (0.95f * v + cur);
  float thr = th0[n] + tn0[toff] * 0.1f;
  bool sp = (!refrac) && (Vn > thr);
  V[idx]  = sp ? 0.f : Vn;
  ls[idx] = sp ? tf : l;
  unsigned long long bal = __ballot(sp);
  if ((threadIdx.x & 63) == 0) bits[idx >> 6] = bal;
  cost_accum(sp ? wnn : 0.f, sp ? 1 : 0, cost, tot, t);
}

// ---------------- layers 1/2: sparse binary matmul + LIF ----------------

template<int NIN, int NOUT, bool LAST>
__global__ __launch_bounds__(256) void lif_sparse_kernel(const unsigned long long* __restrict__ bits_in,
                                                         const float* __restrict__ wT,   // [NIN][NOUT]
                                                         const float* __restrict__ cn,
                                                         const float* __restrict__ tn,
                                                         const float* __restrict__ th,
                                                         const float* __restrict__ wn,
                                                         float* __restrict__ V,
                                                         float* __restrict__ ls,
                                                         unsigned long long* __restrict__ bits_out,
                                                         float* __restrict__ out,
                                                         float* cost, float* tot, int t) {
  constexpr int VEC = NOUT / 256;
  constexpr int NW  = NIN / 64;
  const int b = blockIdx.x;
  const int tid = threadIdx.x;
  float acc[VEC];
  #pragma unroll
  for (int j = 0; j < VEC; ++j) acc[j] = 0.f;

  const unsigned long long* mrow = bits_in + b * NW;
  for (int w = 0; w < NW; ++w) {
    unsigned long long m = mrow[w];
    // force wave-uniform -> scalar branches
    unsigned int lo = (unsigned int)__builtin_amdgcn_readfirstlane((int)(unsigned int)m);
    unsigned int hi = (unsigned int)__builtin_amdgcn_readfirstlane((int)(unsigned int)(m >> 32));
    m = (((unsigned long long)hi) << 32) | lo;
    const float* wbase = wT + (size_t)(w << 6) * NOUT + tid;
    while (m) {
      int kk = __builtin_ctzll(m);
      m &= m - 1;
      const float* row = wbase + (size_t)kk * NOUT;
      #pragma unroll
      for (int j = 0; j < VEC; ++j) acc[j] += row[j * 256];
    }
  }

  const float tf = (float)t;
  const int base = ((t - 1) * B + b) * NOUT;
  const int gib = b * NOUT;
  float csum = 0.f; int cnt = 0;
  #pragma unroll
  for (int j = 0; j < VEC; ++j) {
    int n = j * 256 + tid;
    int gi = gib + n;
    float wnn = wn[n];
    float cur = acc[j] + cn[base + n] * (0.05f * wnn);
    float v = V[gi], l = ls[gi];
    bool refrac = (tf - l) < 2.0f;
    float Vn = refrac ? v : (0.95f * v + cur);
    float thr = th[n] + tn[base + n] * 0.1f;
    bool sp = (!refrac) && (Vn > thr);
    V[gi]  = sp ? 0.f : Vn;
    ls[gi] = sp ? tf : l;
    if (sp) { csum += wnn; cnt++; }
    unsigned long long bal = __ballot(sp);
    if (!LAST) {
      if ((tid & 63) == 0) bits_out[b * (NOUT / 64) + j * 4 + (tid >> 6)] = bal;
    } else {
      out[gi] = sp ? 1.f : 0.f;
    }
  }
  cost_accum(csum, cnt, cost, tot, t);
}

// ---------------- finalize: cost + entropy scalars ----------------

__global__ __launch_bounds__(64) void finalize_kernel(const float* __restrict__ cost,
                                                      const float* __restrict__ tot,
                                                      float* __restrict__ out) {
  if (threadIdx.x == 0) {
    float c = *cost;
    float p1 = *tot / 14680064.f;   // T*B*(2048+1024+512)
    float p0 = 1.f - p1;
    float ent = -(p1 * log2f(p1 + 1e-12f) + p0 * log2f(p0 + 1e-12f));
    out[131072] = c;
    out[131073] = ent;
  }
}

// ---------------- launch ----------------

extern "C" void kernel_launch(void* const* d_in, const int* in_sizes, int n_in,
                              void* d_out, int out_size, void* d_ws, size_t ws_size,
                              hipStream_t stream) {
  const float* inputs = (const float*)d_in[0];
  const float* w0  = (const float*)d_in[1];
  const float* th0 = (const float*)d_in[2];
  const float* cn0 = (const float*)d_in[3];
  const float* tn0 = (const float*)d_in[4];
  const float* w1  = (const float*)d_in[5];
  const float* th1 = (const float*)d_in[6];
  const float* cn1 = (const float*)d_in[7];
  const float* tn1 = (const float*)d_in[8];
  const float* w2  = (const float*)d_in[9];
  const float* th2 = (const float*)d_in[10];
  const float* cn2 = (const float*)d_in[11];
  const float* tn2 = (const float*)d_in[12];
  float* out = (float*)d_out;
  float* ws  = (float*)d_ws;

  // workspace layout (floats)
  float* wn    = ws;                    // 3584: wn0[2048] wn1[1024] wn2[512]
  float* cost  = ws + 3584;
  float* tot   = ws + 3585;
  float* base0 = ws + 4096;             // 524288
  float* V0  = base0 + 524288;          // 524288
  float* V1  = V0 + 524288;             // 262144
  float* V2  = V1 + 262144;             // 131072
  float* LS0 = V2 + 131072;             // 524288
  float* LS1 = LS0 + 524288;            // 262144
  float* LS2 = LS1 + 262144;            // 131072
  float* WT1 = LS2 + 131072;            // 2048*1024
  float* WT2 = WT1 + 2097152;           // 1024*512
  unsigned long long* BITS0 = (unsigned long long*)(WT2 + 524288);  // 256*32 u64
  unsigned long long* BITS1 = BITS0 + 8192;                          // 256*16 u64

  init_kernel<<<3584, 256, 0, stream>>>(V0, LS0, cost, tot);       // V0..V2, LS0..LS2 contiguous
  wnorm_kernel<<<3584, 64, 0, stream>>>(w0, w1, w2, wn);
  transpose_kernel<<<dim3(2048 / 32, 1024 / 32), 256, 0, stream>>>(w1, WT1, 1024, 2048);
  transpose_kernel<<<dim3(1024 / 32, 512 / 32), 256, 0, stream>>>(w2, WT2, 512, 1024);
  base0_kernel<<<dim3(4, 32), 256, 0, stream>>>(inputs, w0, base0);

  for (int t = 1; t <= T_STEPS; ++t) {
    lif0_kernel<<<2048, 256, 0, stream>>>(base0, cn0, tn0, th0, wn, V0, LS0, BITS0, cost, tot, t);
    lif_sparse_kernel<2048, 1024, false><<<256, 256, 0, stream>>>(
        BITS0, WT1, cn1, tn1, th1, wn + 2048, V1, LS1, BITS1, nullptr, cost, tot, t);
    lif_sparse_kernel<1024, 512, true><<<256, 256, 0, stream>>>(
        BITS1, WT2, cn2, tn2, th2, wn + 3072, V2, LS2, nullptr, out, cost, tot, t);
  }
  finalize_kernel<<<1, 64, 0, stream>>>(cost, tot, out);
}

// Round 2
// 1434.585 us; speedup vs baseline: 2.0532x; 2.0532x over previous
//
#include <hip/hip_runtime.h>
#include <math.h>

// NeuromorphicPrivacyNetwork: 3-layer LIF SNN, T=16, B=256, sizes 1024->2048->1024->512.
// Round-2 strategy:
//   - base0 = inputs @ w0^T once, via bf16 hi/lo split MFMA (3 products)
//   - ALL 16 steps of layer 0 in ONE kernel (layer 0 independent of layers 1/2),
//     V/LS in registers, spikes written as u8 [16][256][2048]
//   - layers 1/2: dense MFMA GEMM per step. A = spikes (u8 -> bf16, exact),
//     B = W split hi/lo bf16 on the fly in staging (2 MFMA products), fused LIF epilogue.
//   - cost/entropy accumulated online with trailing-window factor min(10, T-s).

#define B 256
#define T_STEPS 16

typedef short short8 __attribute__((ext_vector_type(8)));
typedef float floatx4 __attribute__((ext_vector_type(4)));

__device__ inline ushort f2bf(float x) {
  unsigned int u = __float_as_uint(x);
  unsigned int r = (u + 0x7FFFu + ((u >> 16) & 1u)) >> 16;
  return (ushort)r;
}
__device__ inline float bf2f(ushort h) {
  return __uint_as_float(((unsigned int)h) << 16);
}

__device__ inline floatx4 mfma16(short8 a, short8 b, floatx4 c) {
  return __builtin_amdgcn_mfma_f32_16x16x32_bf16(a, b, c, 0, 0, 0);
}

// stage 16 fp32 -> hi/lo bf16 pairs into LDS (dsth/dstl point at ushort[16] runs, 16B aligned)
__device__ inline void stage_split16(const float* __restrict__ src, ushort* dsth, ushort* dstl) {
  float fv[16];
  #pragma unroll
  for (int i = 0; i < 4; ++i) *(float4*)&fv[4 * i] = *(const float4*)(src + 4 * i);
  unsigned int ph[8], pl[8];
  #pragma unroll
  for (int i = 0; i < 8; ++i) {
    ushort h0 = f2bf(fv[2 * i]);
    ushort l0 = f2bf(fv[2 * i] - bf2f(h0));
    ushort h1 = f2bf(fv[2 * i + 1]);
    ushort l1 = f2bf(fv[2 * i + 1] - bf2f(h1));
    ph[i] = (unsigned int)h0 | ((unsigned int)h1 << 16);
    pl[i] = (unsigned int)l0 | ((unsigned int)l1 << 16);
  }
  *(uint4*)dsth       = make_uint4(ph[0], ph[1], ph[2], ph[3]);
  *(uint4*)(dsth + 8) = make_uint4(ph[4], ph[5], ph[6], ph[7]);
  *(uint4*)dstl       = make_uint4(pl[0], pl[1], pl[2], pl[3]);
  *(uint4*)(dstl + 8) = make_uint4(pl[4], pl[5], pl[6], pl[7]);
}

// stage 16 u8 spikes -> bf16 {0,1} into LDS
__device__ inline void stage_spk16(const unsigned char* __restrict__ src, ushort* dst) {
  uint4 q = *(const uint4*)src;
  unsigned int w, p[8];
  w = q.x;
  p[0] = ((w & 0x000000FFu) ? 0x00003F80u : 0u) | ((w & 0x0000FF00u) ? 0x3F800000u : 0u);
  p[1] = ((w & 0x00FF0000u) ? 0x00003F80u : 0u) | ((w & 0xFF000000u) ? 0x3F800000u : 0u);
  w = q.y;
  p[2] = ((w & 0x000000FFu) ? 0x00003F80u : 0u) | ((w & 0x0000FF00u) ? 0x3F800000u : 0u);
  p[3] = ((w & 0x00FF0000u) ? 0x00003F80u : 0u) | ((w & 0xFF000000u) ? 0x3F800000u : 0u);
  w = q.z;
  p[4] = ((w & 0x000000FFu) ? 0x00003F80u : 0u) | ((w & 0x0000FF00u) ? 0x3F800000u : 0u);
  p[5] = ((w & 0x00FF0000u) ? 0x00003F80u : 0u) | ((w & 0xFF000000u) ? 0x3F800000u : 0u);
  w = q.w;
  p[6] = ((w & 0x000000FFu) ? 0x00003F80u : 0u) | ((w & 0x0000FF00u) ? 0x3F800000u : 0u);
  p[7] = ((w & 0x00FF0000u) ? 0x00003F80u : 0u) | ((w & 0xFF000000u) ? 0x3F800000u : 0u);
  *(uint4*)dst       = make_uint4(p[0], p[1], p[2], p[3]);
  *(uint4*)(dst + 8) = make_uint4(p[4], p[5], p[6], p[7]);
}

// block reduce + atomic; csum already includes the trailing-window factor
__device__ inline void cost_accum_raw(float csum, int cnt, float* cost, float* tot) {
  #pragma unroll
  for (int off = 32; off > 0; off >>= 1) {
    csum += __shfl_down(csum, off);
    cnt  += __shfl_down(cnt, off);
  }
  __shared__ float sc[4];
  __shared__ int   si[4];
  int wid = threadIdx.x >> 6;
  if ((threadIdx.x & 63) == 0) { sc[wid] = csum; si[wid] = cnt; }
  __syncthreads();
  if (threadIdx.x == 0) {
    float c = sc[0] + sc[1] + sc[2] + sc[3];
    int   k = si[0] + si[1] + si[2] + si[3];
    atomicAdd(cost, c * 0.01f);   // per-spike cost = 0.1 * fac/10 * wn = 0.01*fac*wn
    atomicAdd(tot, (float)k);
  }
}

// ---------------- init ----------------

__global__ __launch_bounds__(256) void init_kernel(float* __restrict__ Vr,
                                                   float* __restrict__ LSr,
                                                   float* __restrict__ cost,
                                                   float* __restrict__ tot) {
  int idx = blockIdx.x * 256 + threadIdx.x;  // 393216 each
  Vr[idx]  = 0.f;
  LSr[idx] = -1e9f;
  if (idx == 0) { *cost = 0.f; *tot = 0.f; }
}

// ---------------- weight row norms ----------------

__global__ __launch_bounds__(64) void wnorm_kernel(const float* __restrict__ w0,
                                                   const float* __restrict__ w1,
                                                   const float* __restrict__ w2,
                                                   float* __restrict__ wn) {
  int r = blockIdx.x;  // 0..3583
  const float* row; int K;
  if (r < 2048)      { row = w0 + (size_t)r * 1024;          K = 1024; }
  else if (r < 3072) { row = w1 + (size_t)(r - 2048) * 2048; K = 2048; }
  else               { row = w2 + (size_t)(r - 3072) * 1024; K = 1024; }
  float ss = 0.f;
  for (int k = threadIdx.x; k < K; k += 64) { float x = row[k]; ss += x * x; }
  #pragma unroll
  for (int off = 32; off > 0; off >>= 1) ss += __shfl_down(ss, off);
  if (threadIdx.x == 0) wn[r] = sqrtf(ss);
}

// ---------------- base0 = inputs @ w0^T via split MFMA ----------------

__global__ __launch_bounds__(256) void base0_mfma_kernel(const float* __restrict__ A,  // [256][1024]
                                                         const float* __restrict__ W,  // [2048][1024]
                                                         float* __restrict__ C) {      // [256][2048]
  __shared__ ushort Ah[64][72], Al[64][72], Bh[64][72], Bl[64][72];
  const int tid = threadIdx.x;
  const int m0 = blockIdx.x * 64;
  const int n0 = blockIdx.y * 64;
  const int lane = tid & 63, wv = tid >> 6;
  const int wm = wv & 1, wn2 = wv >> 1;
  const int l15 = lane & 15, quad = lane >> 4;
  const int sr = tid >> 2, scol = (tid & 3) * 16;

  floatx4 acc[2][2];
  #pragma unroll
  for (int i = 0; i < 2; ++i)
    #pragma unroll
    for (int j = 0; j < 2; ++j) acc[i][j] = (floatx4){0.f, 0.f, 0.f, 0.f};

  for (int k0 = 0; k0 < 1024; k0 += 64) {
    stage_split16(A + (size_t)(m0 + sr) * 1024 + k0 + scol, &Ah[sr][scol], &Al[sr][scol]);
    stage_split16(W + (size_t)(n0 + sr) * 1024 + k0 + scol, &Bh[sr][scol], &Bl[sr][scol]);
    __syncthreads();
    #pragma unroll
    for (int ks = 0; ks < 2; ++ks) {
      short8 ah[2], al[2], bh[2], bl[2];
      #pragma unroll
      for (int s = 0; s < 2; ++s) {
        ah[s] = *(const short8*)&Ah[32 * wm + 16 * s + l15][ks * 32 + quad * 8];
        al[s] = *(const short8*)&Al[32 * wm + 16 * s + l15][ks * 32 + quad * 8];
        bh[s] = *(const short8*)&Bh[32 * wn2 + 16 * s + l15][ks * 32 + quad * 8];
        bl[s] = *(const short8*)&Bl[32 * wn2 + 16 * s + l15][ks * 32 + quad * 8];
      }
      #pragma unroll
      for (int sm = 0; sm < 2; ++sm)
        #pragma unroll
        for (int sn = 0; sn < 2; ++sn) {
          acc[sm][sn] = mfma16(ah[sm], bh[sn], acc[sm][sn]);
          acc[sm][sn] = mfma16(ah[sm], bl[sn], acc[sm][sn]);
          acc[sm][sn] = mfma16(al[sm], bh[sn], acc[sm][sn]);
        }
    }
    __syncthreads();
  }
  #pragma unroll
  for (int sm = 0; sm < 2; ++sm)
    #pragma unroll
    for (int sn = 0; sn < 2; ++sn)
      #pragma unroll
      for (int r = 0; r < 4; ++r) {
        int m = m0 + 32 * wm + 16 * sm + quad * 4 + r;
        int n = n0 + 32 * wn2 + 16 * sn + l15;
        C[(size_t)m * 2048 + n] = acc[sm][sn][r];
      }
}

// ---------------- all 16 steps of layer 0 (state in registers) ----------------

__global__ __launch_bounds__(256) void lif0_all_kernel(const float* __restrict__ base0,
                                                       const float* __restrict__ cn0,
                                                       const float* __restrict__ tn0,
                                                       const float* __restrict__ th0,
                                                       const float* __restrict__ wn,
                                                       unsigned char* __restrict__ sp0,
                                                       float* cost, float* tot) {
  int idx = blockIdx.x * 256 + threadIdx.x;  // 524288 total
  int n = idx & 2047;
  float wnn = wn[n];
  float thb = th0[n];
  float bb = base0[idx];
  float v = 0.f, l = -1e9f;
  float csum = 0.f; int cnt = 0;
  #pragma unroll
  for (int t = 1; t <= T_STEPS; ++t) {
    int off = (t - 1) * (B * 2048) + idx;
    float cur = bb + cn0[off] * (0.05f * wnn);
    float tf = (float)t;
    bool refrac = (tf - l) < 2.0f;
    float Vn = refrac ? v : (0.95f * v + cur);
    float thr = thb + tn0[off] * 0.1f;
    bool sp = (!refrac) && (Vn > thr);
    v = sp ? 0.f : Vn;
    l = sp ? tf : l;
    int f = T_STEPS - (t - 1); if (f > 10) f = 10;
    if (sp) { csum += wnn * (float)f; cnt++; }
    sp0[off] = sp ? (unsigned char)1 : (unsigned char)0;
  }
  cost_accum_raw(csum, cnt, cost, tot);
}

// ---------------- layers 1/2: dense MFMA GEMM + fused LIF ----------------

template<int K, int N, bool LAST>
__global__ __launch_bounds__(256) void gemm_lif_kernel(const unsigned char* __restrict__ spin, // [256][K]
                                                       const float* __restrict__ w,           // [N][K]
                                                       const float* __restrict__ cn,
                                                       const float* __restrict__ tn,
                                                       const float* __restrict__ th,
                                                       const float* __restrict__ wn,
                                                       float* __restrict__ V,
                                                       float* __restrict__ ls,
                                                       unsigned char* __restrict__ spout,
                                                       float* __restrict__ out,
                                                       float* cost, float* tot, int t) {
  __shared__ ushort As[64][72], Bh[64][72], Bl[64][72];
  const int tid = threadIdx.x;
  const int m0 = blockIdx.x * 64;
  const int n0 = blockIdx.y * 64;
  const int lane = tid & 63, wv = tid >> 6;
  const int wm = wv & 1, wn2 = wv >> 1;
  const int l15 = lane & 15, quad = lane >> 4;
  const int sr = tid >> 2, scol = (tid & 3) * 16;

  floatx4 acc[2][2];
  #pragma unroll
  for (int i = 0; i < 2; ++i)
    #pragma unroll
    for (int j = 0; j < 2; ++j) acc[i][j] = (floatx4){0.f, 0.f, 0.f, 0.f};

  for (int k0 = 0; k0 < K; k0 += 64) {
    stage_spk16(spin + (size_t)(m0 + sr) * K + k0 + scol, &As[sr][scol]);
    stage_split16(w + (size_t)(n0 + sr) * K + k0 + scol, &Bh[sr][scol], &Bl[sr][scol]);
    __syncthreads();
    #pragma unroll
    for (int ks = 0; ks < 2; ++ks) {
      short8 a[2], bh[2], bl[2];
      #pragma unroll
      for (int s = 0; s < 2; ++s) {
        a[s]  = *(const short8*)&As[32 * wm + 16 * s + l15][ks * 32 + quad * 8];
        bh[s] = *(const short8*)&Bh[32 * wn2 + 16 * s + l15][ks * 32 + quad * 8];
        bl[s] = *(const short8*)&Bl[32 * wn2 + 16 * s + l15][ks * 32 + quad * 8];
      }
      #pragma unroll
      for (int sm = 0; sm < 2; ++sm)
        #pragma unroll
        for (int sn = 0; sn < 2; ++sn) {
          acc[sm][sn] = mfma16(a[sm], bh[sn], acc[sm][sn]);
          acc[sm][sn] = mfma16(a[sm], bl[sn], acc[sm][sn]);
        }
    }
    __syncthreads();
  }

  const float tf = (float)t;
  float csum = 0.f; int cnt = 0;
  #pragma unroll
  for (int sm = 0; sm < 2; ++sm)
    #pragma unroll
    for (int sn = 0; sn < 2; ++sn)
      #pragma unroll
      for (int r = 0; r < 4; ++r) {
        int m = m0 + 32 * wm + 16 * sm + quad * 4 + r;
        int n = n0 + 32 * wn2 + 16 * sn + l15;
        int gi = m * N + n;
        int cb = ((t - 1) * B + m) * N + n;
        float wnn = wn[n];
        float cur = acc[sm][sn][r] + cn[cb] * (0.05f * wnn);
        float v = V[gi], l = ls[gi];
        bool refrac = (tf - l) < 2.0f;
        float Vn = refrac ? v : (0.95f * v + cur);
        float thr = th[n] + tn[cb] * 0.1f;
        bool sp = (!refrac) && (Vn > thr);
        V[gi]  = sp ? 0.f : Vn;
        ls[gi] = sp ? tf : l;
        if (sp) { csum += wnn; cnt++; }
        if (LAST) out[gi] = sp ? 1.f : 0.f;
        else      spout[gi] = sp ? (unsigned char)1 : (unsigned char)0;
      }
  int f = T_STEPS - (t - 1); if (f > 10) f = 10;
  cost_accum_raw(csum * (float)f, cnt, cost, tot);
}

// ---------------- finalize ----------------

__global__ __launch_bounds__(64) void finalize_kernel(const float* __restrict__ cost,
                                                      const float* __restrict__ tot,
                                                      float* __restrict__ out) {
  if (threadIdx.x == 0) {
    float c = *cost;
    float p1 = *tot / 14680064.f;   // T*B*(2048+1024+512)
    float p0 = 1.f - p1;
    float ent = -(p1 * log2f(p1 + 1e-12f) + p0 * log2f(p0 + 1e-12f));
    out[131072] = c;
    out[131073] = ent;
  }
}

// ---------------- launch ----------------

extern "C" void kernel_launch(void* const* d_in, const int* in_sizes, int n_in,
                              void* d_out, int out_size, void* d_ws, size_t ws_size,
                              hipStream_t stream) {
  const float* inputs = (const float*)d_in[0];
  const float* w0  = (const float*)d_in[1];
  const float* th0 = (const float*)d_in[2];
  const float* cn0 = (const float*)d_in[3];
  const float* tn0 = (const float*)d_in[4];
  const float* w1  = (const float*)d_in[5];
  const float* th1 = (const float*)d_in[6];
  const float* cn1 = (const float*)d_in[7];
  const float* tn1 = (const float*)d_in[8];
  const float* w2  = (const float*)d_in[9];
  const float* th2 = (const float*)d_in[10];
  const float* cn2 = (const float*)d_in[11];
  const float* tn2 = (const float*)d_in[12];
  float* out = (float*)d_out;
  float* ws  = (float*)d_ws;

  // workspace layout (floats) — total ~3.48M floats (~14 MB)
  float* wn    = ws;                        // 3584
  float* cost  = ws + 3584;
  float* tot   = ws + 3585;
  float* base0 = ws + 4096;                 // 524288
  float* Vr    = base0 + 524288;            // 393216: V1[262144] V2[131072]
  float* LSr   = Vr + 393216;               // 393216: LS1 LS2
  unsigned char* sp0 = (unsigned char*)(LSr + 393216);  // 16*524288 = 8 MB
  unsigned char* sp1 = sp0 + 16 * 524288;               // 262144 B
  float* V1 = Vr,  * V2 = Vr + 262144;
  float* LS1 = LSr, * LS2 = LSr + 262144;

  init_kernel<<<1536, 256, 0, stream>>>(Vr, LSr, cost, tot);
  wnorm_kernel<<<3584, 64, 0, stream>>>(w0, w1, w2, wn);
  base0_mfma_kernel<<<dim3(4, 32), 256, 0, stream>>>(inputs, w0, base0);
  lif0_all_kernel<<<2048, 256, 0, stream>>>(base0, cn0, tn0, th0, wn, sp0, cost, tot);

  for (int t = 1; t <= T_STEPS; ++t) {
    gemm_lif_kernel<2048, 1024, false><<<dim3(4, 16), 256, 0, stream>>>(
        sp0 + (size_t)(t - 1) * 524288, w1, cn1, tn1, th1, wn + 2048,
        V1, LS1, sp1, nullptr, cost, tot, t);
    gemm_lif_kernel<1024, 512, true><<<dim3(4, 8), 256, 0, stream>>>(
        sp1, w2, cn2, tn2, th2, wn + 3072,
        V2, LS2, nullptr, out, cost, tot, t);
  }
  finalize_kernel<<<1, 64, 0, stream>>>(cost, tot, out);
}

// Round 3
// 898.644 us; speedup vs baseline: 3.2777x; 1.5964x over previous
//
#include <hip/hip_runtime.h>
#include <math.h>

// NeuromorphicPrivacyNetwork: 3-layer LIF SNN, T=16, B=256, sizes 1024->2048->1024->512.
// Round-3 strategy:
//   - preconvert W1/W2 -> bf16 once (spike-flip tolerance proven by rounds 1/2)
//   - software-pipelined steps: dispatch d runs L0(d+1) | L1(d) | L2(d-1) on 224 blocks
//   - GEMMs load MFMA fragments DIRECTLY from global (b128), register prefetch, no LDS
//   - refractory state = "spiked last step" = previous spike buffer (no last-spike arrays)
//   - cost/entropy accumulated online with trailing-window factor min(10, 17-t)

#define B 256
#define T_STEPS 16

typedef short short8 __attribute__((ext_vector_type(8)));
typedef float floatx4 __attribute__((ext_vector_type(4)));

__device__ inline ushort f2bf(float x) {
  unsigned int u = __float_as_uint(x);
  unsigned int r = (u + 0x7FFFu + ((u >> 16) & 1u)) >> 16;
  return (ushort)r;
}
__device__ inline float bf2f(ushort h) {
  return __uint_as_float(((unsigned int)h) << 16);
}
__device__ inline floatx4 mfma16(short8 a, short8 b, floatx4 c) {
  return __builtin_amdgcn_mfma_f32_16x16x32_bf16(a, b, c, 0, 0, 0);
}

// stage 16 fp32 -> hi/lo bf16 pairs into LDS (base0 only)
__device__ inline void stage_split16(const float* __restrict__ src, ushort* dsth, ushort* dstl) {
  float fv[16];
  #pragma unroll
  for (int i = 0; i < 4; ++i) *(float4*)&fv[4 * i] = *(const float4*)(src + 4 * i);
  unsigned int ph[8], pl[8];
  #pragma unroll
  for (int i = 0; i < 8; ++i) {
    ushort h0 = f2bf(fv[2 * i]);
    ushort l0 = f2bf(fv[2 * i] - bf2f(h0));
    ushort h1 = f2bf(fv[2 * i + 1]);
    ushort l1 = f2bf(fv[2 * i + 1] - bf2f(h1));
    ph[i] = (unsigned int)h0 | ((unsigned int)h1 << 16);
    pl[i] = (unsigned int)l0 | ((unsigned int)l1 << 16);
  }
  *(uint4*)dsth       = make_uint4(ph[0], ph[1], ph[2], ph[3]);
  *(uint4*)(dsth + 8) = make_uint4(ph[4], ph[5], ph[6], ph[7]);
  *(uint4*)dstl       = make_uint4(pl[0], pl[1], pl[2], pl[3]);
  *(uint4*)(dstl + 8) = make_uint4(pl[4], pl[5], pl[6], pl[7]);
}

__device__ inline void cost_accum_raw(float csum, int cnt, float* cost, float* tot) {
  #pragma unroll
  for (int off = 32; off > 0; off >>= 1) {
    csum += __shfl_down(csum, off);
    cnt  += __shfl_down(cnt, off);
  }
  __shared__ float sc[4];
  __shared__ int   si[4];
  int wid = threadIdx.x >> 6;
  if ((threadIdx.x & 63) == 0) { sc[wid] = csum; si[wid] = cnt; }
  __syncthreads();
  if (threadIdx.x == 0) {
    float c = sc[0] + sc[1] + sc[2] + sc[3];
    int   k = si[0] + si[1] + si[2] + si[3];
    atomicAdd(cost, c * 0.01f);
    atomicAdd(tot, (float)k);
  }
}

// ---------------- init: zero V0,V1,V2 (contiguous) + scalars ----------------

__global__ __launch_bounds__(256) void init_kernel(float* __restrict__ Vall,
                                                   float* __restrict__ cost,
                                                   float* __restrict__ tot) {
  int idx = blockIdx.x * 256 + threadIdx.x;  // 917504 exactly (3584 blocks)
  Vall[idx] = 0.f;
  if (idx == 0) { *cost = 0.f; *tot = 0.f; }
}

// ---------------- weight row norms ----------------

__global__ __launch_bounds__(64) void wnorm_kernel(const float* __restrict__ w0,
                                                   const float* __restrict__ w1,
                                                   const float* __restrict__ w2,
                                                   float* __restrict__ wn) {
  int r = blockIdx.x;  // 0..3583
  const float* row; int K;
  if (r < 2048)      { row = w0 + (size_t)r * 1024;          K = 1024; }
  else if (r < 3072) { row = w1 + (size_t)(r - 2048) * 2048; K = 2048; }
  else               { row = w2 + (size_t)(r - 3072) * 1024; K = 1024; }
  float ss = 0.f;
  for (int k = threadIdx.x; k < K; k += 64) { float x = row[k]; ss += x * x; }
  #pragma unroll
  for (int off = 32; off > 0; off >>= 1) ss += __shfl_down(ss, off);
  if (threadIdx.x == 0) wn[r] = sqrtf(ss);
}

// ---------------- convert W1,W2 -> bf16 ----------------

__global__ __launch_bounds__(256) void convert_w_kernel(const float* __restrict__ w1,
                                                        const float* __restrict__ w2,
                                                        ushort* __restrict__ w1b,
                                                        ushort* __restrict__ w2b) {
  int i = (blockIdx.x * 256 + threadIdx.x) * 8;   // 1280 blocks -> 2621440 elems
  const float* src; ushort* dst;
  if (i < 2097152) { src = w1 + i; dst = w1b + i; }
  else             { src = w2 + (i - 2097152); dst = w2b + (i - 2097152); }
  float4 a = *(const float4*)src;
  float4 b = *(const float4*)(src + 4);
  unsigned int p0 = (unsigned int)f2bf(a.x) | ((unsigned int)f2bf(a.y) << 16);
  unsigned int p1 = (unsigned int)f2bf(a.z) | ((unsigned int)f2bf(a.w) << 16);
  unsigned int p2 = (unsigned int)f2bf(b.x) | ((unsigned int)f2bf(b.y) << 16);
  unsigned int p3 = (unsigned int)f2bf(b.z) | ((unsigned int)f2bf(b.w) << 16);
  *(uint4*)dst = make_uint4(p0, p1, p2, p3);
}

// ---------------- base0 = inputs @ w0^T via split MFMA (one-time) ----------------

__global__ __launch_bounds__(256) void base0_mfma_kernel(const float* __restrict__ A,  // [256][1024]
                                                         const float* __restrict__ W,  // [2048][1024]
                                                         float* __restrict__ C) {      // [256][2048]
  __shared__ ushort Ah[64][72], Al[64][72], Bh[64][72], Bl[64][72];
  const int tid = threadIdx.x;
  const int m0 = blockIdx.x * 64;
  const int n0 = blockIdx.y * 64;
  const int lane = tid & 63, wv = tid >> 6;
  const int wm = wv & 1, wn2 = wv >> 1;
  const int l15 = lane & 15, quad = lane >> 4;
  const int sr = tid >> 2, scol = (tid & 3) * 16;

  floatx4 acc[2][2];
  #pragma unroll
  for (int i = 0; i < 2; ++i)
    #pragma unroll
    for (int j = 0; j < 2; ++j) acc[i][j] = (floatx4){0.f, 0.f, 0.f, 0.f};

  for (int k0 = 0; k0 < 1024; k0 += 64) {
    stage_split16(A + (size_t)(m0 + sr) * 1024 + k0 + scol, &Ah[sr][scol], &Al[sr][scol]);
    stage_split16(W + (size_t)(n0 + sr) * 1024 + k0 + scol, &Bh[sr][scol], &Bl[sr][scol]);
    __syncthreads();
    #pragma unroll
    for (int ks = 0; ks < 2; ++ks) {
      short8 ah[2], al[2], bh[2], bl[2];
      #pragma unroll
      for (int s = 0; s < 2; ++s) {
        ah[s] = *(const short8*)&Ah[32 * wm + 16 * s + l15][ks * 32 + quad * 8];
        al[s] = *(const short8*)&Al[32 * wm + 16 * s + l15][ks * 32 + quad * 8];
        bh[s] = *(const short8*)&Bh[32 * wn2 + 16 * s + l15][ks * 32 + quad * 8];
        bl[s] = *(const short8*)&Bl[32 * wn2 + 16 * s + l15][ks * 32 + quad * 8];
      }
      #pragma unroll
      for (int sm = 0; sm < 2; ++sm)
        #pragma unroll
        for (int sn = 0; sn < 2; ++sn) {
          acc[sm][sn] = mfma16(ah[sm], bh[sn], acc[sm][sn]);
          acc[sm][sn] = mfma16(ah[sm], bl[sn], acc[sm][sn]);
          acc[sm][sn] = mfma16(al[sm], bh[sn], acc[sm][sn]);
        }
    }
    __syncthreads();
  }
  #pragma unroll
  for (int sm = 0; sm < 2; ++sm)
    #pragma unroll
    for (int sn = 0; sn < 2; ++sn)
      #pragma unroll
      for (int r = 0; r < 4; ++r) {
        int m = m0 + 32 * wm + 16 * sm + quad * 4 + r;
        int n = n0 + 32 * wn2 + 16 * sn + l15;
        C[(size_t)m * 2048 + n] = acc[sm][sn][r];
      }
}

// ---------------- GEMM+LIF body: direct-global MFMA fragments ----------------

template<int K>
__device__ inline void ld_frags(const ushort* __restrict__ Abase,
                                const ushort* __restrict__ Wbase,
                                int l15, int k0, uint4 fa[2][2], uint4 fb[2][2]) {
  #pragma unroll
  for (int ks = 0; ks < 2; ++ks)
    #pragma unroll
    for (int s = 0; s < 2; ++s) {
      fa[ks][s] = *(const uint4*)(Abase + (size_t)(16 * s + l15) * K + k0 + ks * 32);
      fb[ks][s] = *(const uint4*)(Wbase + (size_t)(16 * s + l15) * K + k0 + ks * 32);
    }
}

template<int K, int N, bool WRITESP>
__device__ void gemm_lif(const ushort* __restrict__ A,     // [256][K] bf16 spikes
                         const ushort* __restrict__ W,     // [N][K] bf16
                         const ushort* __restrict__ sppr,  // [256][N] prev spikes (refrac)
                         ushort* __restrict__ spout,       // [256][N] (if WRITESP)
                         const float* __restrict__ cn, const float* __restrict__ tn,
                         const float* __restrict__ th, const float* __restrict__ wnv,
                         float* __restrict__ V, float* __restrict__ outF, bool writeOut,
                         float* cost, float* tot, int t, int bid) {
  const int tid = threadIdx.x;
  const int m0 = (bid & 3) * 64, n0 = (bid >> 2) * 64;
  const int lane = tid & 63, wv = tid >> 6;
  const int wm = wv & 1, wn2 = wv >> 1;
  const int l15 = lane & 15, quad = lane >> 4;

  const ushort* Abase = A + (size_t)(m0 + 32 * wm) * K + quad * 8;
  const ushort* Wbase = W + (size_t)(n0 + 32 * wn2) * K + quad * 8;

  floatx4 acc[2][2];
  #pragma unroll
  for (int i = 0; i < 2; ++i)
    #pragma unroll
    for (int j = 0; j < 2; ++j) acc[i][j] = (floatx4){0.f, 0.f, 0.f, 0.f};

  uint4 fa[2][2], fb[2][2];
  ld_frags<K>(Abase, Wbase, l15, 0, fa, fb);
  for (int k0 = 0; k0 < K; k0 += 64) {
    uint4 na[2][2], nb[2][2];
    if (k0 + 64 < K) ld_frags<K>(Abase, Wbase, l15, k0 + 64, na, nb);
    #pragma unroll
    for (int ks = 0; ks < 2; ++ks)
      #pragma unroll
      for (int sm = 0; sm < 2; ++sm)
        #pragma unroll
        for (int sn = 0; sn < 2; ++sn)
          acc[sm][sn] = mfma16(*(const short8*)&fa[ks][sm], *(const short8*)&fb[ks][sn], acc[sm][sn]);
    #pragma unroll
    for (int ks = 0; ks < 2; ++ks)
      #pragma unroll
      for (int s = 0; s < 2; ++s) { fa[ks][s] = na[ks][s]; fb[ks][s] = nb[ks][s]; }
  }

  const float tf = (float)t;
  float csum = 0.f; int cnt = 0;
  #pragma unroll
  for (int sm = 0; sm < 2; ++sm)
    #pragma unroll
    for (int sn = 0; sn < 2; ++sn)
      #pragma unroll
      for (int r = 0; r < 4; ++r) {
        int m = m0 + 32 * wm + 16 * sm + quad * 4 + r;
        int n = n0 + 32 * wn2 + 16 * sn + l15;
        int gi = m * N + n;
        int cb = ((t - 1) * B + m) * N + n;
        float wnn = wnv[n];
        float cur = acc[sm][sn][r] + cn[cb] * (0.05f * wnn);
        float v = V[gi];
        bool refrac = (t > 1) && (sppr[gi] != 0);
        float Vn = refrac ? v : (0.95f * v + cur);
        float thr = th[n] + tn[cb] * 0.1f;
        bool sp = (!refrac) && (Vn > thr);
        V[gi] = sp ? 0.f : Vn;
        if (WRITESP)  spout[gi] = sp ? (ushort)0x3F80 : (ushort)0;
        else if (writeOut) outF[gi] = sp ? 1.f : 0.f;
        if (sp) { csum += wnn; cnt++; }
      }
  int f = 17 - t; if (f > 10) f = 10;
  cost_accum_raw(csum * (float)f, cnt, cost, tot);
  (void)tf;
}

// ---------------- pipelined step kernel: L0(t+1) | L1(t) | L2(t-1) ----------------

__global__ __launch_bounds__(256) void step_kernel(
    const float* __restrict__ base0, const float* __restrict__ cn0, const float* __restrict__ tn0,
    const float* __restrict__ th0, const float* __restrict__ wn0, float* __restrict__ V0,
    ushort* __restrict__ sp0a, ushort* __restrict__ sp0b,
    const ushort* __restrict__ w1b,
    const float* __restrict__ cn1, const float* __restrict__ tn1,
    const float* __restrict__ th1, const float* __restrict__ wn1, float* __restrict__ V1,
    ushort* __restrict__ sp1a, ushort* __restrict__ sp1b,
    const ushort* __restrict__ w2b,
    const float* __restrict__ cn2, const float* __restrict__ tn2,
    const float* __restrict__ th2, const float* __restrict__ wn2, float* __restrict__ V2,
    ushort* __restrict__ sp2a, ushort* __restrict__ sp2b,
    float* __restrict__ out, float* cost, float* tot, int d) {
  int bid = blockIdx.x;
  if (bid < 64) {
    // layer 1 at step t = d
    int t = d;
    if (t < 1 || t > 16) return;
    const ushort* A = (t & 1) ? sp0b : sp0a;      // sp0[t&1]: 1->b? careful: buffer index = t&1
    // buffer naming: buf[0]=sp0a, buf[1]=sp0b
    A = (t & 1) ? sp0b : sp0a;
    const ushort* pr = ((t - 1) & 1) ? sp1b : sp1a;
    ushort* so = (t & 1) ? sp1b : sp1a;
    gemm_lif<2048, 1024, true>(A, w1b, pr, so, cn1, tn1, th1, wn1, V1, nullptr, false,
                               cost, tot, t, bid);
  } else if (bid < 96) {
    // layer 2 at step t2 = d-1
    int t2 = d - 1;
    if (t2 < 1 || t2 > 16) return;
    const ushort* A = (t2 & 1) ? sp1b : sp1a;
    const ushort* pr = ((t2 - 1) & 1) ? sp2b : sp2a;
    ushort* so = (t2 & 1) ? sp2b : sp2a;
    gemm_lif<1024, 512, true>(A, w2b, pr, so, cn2, tn2, th2, wn2, V2,
                              nullptr, false, cost, tot, t2, bid - 64);
    if (t2 == 16) {
      // also write float out from the just-computed spikes? handled below instead
    }
  } else {
    // layer 0 at step s = d+1
    int s = d + 1;
    if (s > 16) return;
    int base = ((bid - 96) * 256 + threadIdx.x) * 16;   // 128 blocks cover 524288
    int n0i = base & 2047;
    const ushort* pr = ((s - 1) & 1) ? sp0b : sp0a;
    ushort* so = (s & 1) ? sp0b : sp0a;
    size_t off = (size_t)(s - 1) * 524288 + base;
    float tf = (float)s;
    float csum = 0.f; int cnt = 0;
    #pragma unroll
    for (int c = 0; c < 4; ++c) {
      int e = base + c * 4;
      float4 bb  = *(const float4*)(base0 + e);
      float4 vv  = *(const float4*)(V0 + e);
      float4 c4  = *(const float4*)(cn0 + off + c * 4);
      float4 t4  = *(const float4*)(tn0 + off + c * 4);
      float4 th4 = *(const float4*)(th0 + n0i + c * 4);
      float4 wn4 = *(const float4*)(wn0 + n0i + c * 4);
      ushort prv[4] = {0, 0, 0, 0};
      if (s > 1) { ushort4 p = *(const ushort4*)(pr + e); prv[0] = p.x; prv[1] = p.y; prv[2] = p.z; prv[3] = p.w; }
      float bbv[4] = {bb.x, bb.y, bb.z, bb.w};
      float vvv[4] = {vv.x, vv.y, vv.z, vv.w};
      float cnv[4] = {c4.x, c4.y, c4.z, c4.w};
      float tnv[4] = {t4.x, t4.y, t4.z, t4.w};
      float thv[4] = {th4.x, th4.y, th4.z, th4.w};
      float wnv[4] = {wn4.x, wn4.y, wn4.z, wn4.w};
      ushort sout[4];
      float vout[4];
      #pragma unroll
      for (int j = 0; j < 4; ++j) {
        float wnn = wnv[j];
        float cur = bbv[j] + cnv[j] * (0.05f * wnn);
        bool refrac = (s > 1) && (prv[j] != 0);
        float Vn = refrac ? vvv[j] : (0.95f * vvv[j] + cur);
        float thr = thv[j] + tnv[j] * 0.1f;
        bool sp = (!refrac) && (Vn > thr);
        vout[j] = sp ? 0.f : Vn;
        sout[j] = sp ? (ushort)0x3F80 : (ushort)0;
        if (sp) { csum += wnn; cnt++; }
      }
      *(float4*)(V0 + e) = make_float4(vout[0], vout[1], vout[2], vout[3]);
      ushort4 sq; sq.x = sout[0]; sq.y = sout[1]; sq.z = sout[2]; sq.w = sout[3];
      *(ushort4*)(so + e) = sq;
    }
    int f = 17 - s; if (f > 10) f = 10;
    cost_accum_raw(csum * (float)f, cnt, cost, tot);
    (void)tf;
  }
}

// ---------------- write float out from final layer-2 spikes ----------------

__global__ __launch_bounds__(256) void writeout_kernel(const ushort* __restrict__ sp2fin,
                                                       float* __restrict__ out) {
  int i = blockIdx.x * 256 + threadIdx.x;   // 512 blocks -> 131072
  out[i] = (sp2fin[i] != 0) ? 1.f : 0.f;
}

// ---------------- finalize ----------------

__global__ __launch_bounds__(64) void finalize_kernel(const float* __restrict__ cost,
                                                      const float* __restrict__ tot,
                                                      float* __restrict__ out) {
  if (threadIdx.x == 0) {
    float c = *cost;
    float p1 = *tot / 14680064.f;   // T*B*(2048+1024+512)
    float p0 = 1.f - p1;
    float ent = -(p1 * log2f(p1 + 1e-12f) + p0 * log2f(p0 + 1e-12f));
    out[131072] = c;
    out[131073] = ent;
  }
}

// ---------------- launch ----------------

extern "C" void kernel_launch(void* const* d_in, const int* in_sizes, int n_in,
                              void* d_out, int out_size, void* d_ws, size_t ws_size,
                              hipStream_t stream) {
  const float* inputs = (const float*)d_in[0];
  const float* w0  = (const float*)d_in[1];
  const float* th0 = (const float*)d_in[2];
  const float* cn0 = (const float*)d_in[3];
  const float* tn0 = (const float*)d_in[4];
  const float* w1  = (const float*)d_in[5];
  const float* th1 = (const float*)d_in[6];
  const float* cn1 = (const float*)d_in[7];
  const float* tn1 = (const float*)d_in[8];
  const float* w2  = (const float*)d_in[9];
  const float* th2 = (const float*)d_in[10];
  const float* cn2 = (const float*)d_in[11];
  const float* tn2 = (const float*)d_in[12];
  float* out = (float*)d_out;
  float* ws  = (float*)d_ws;

  // workspace layout (float slots), total 3674112 floats = 14.7 MB
  float* wn    = ws;                    // 3584: wn0[2048] wn1[1024] wn2[512]
  float* cost  = ws + 3584;
  float* tot   = ws + 3585;
  float* base0 = ws + 4096;             // 524288
  float* V0    = base0 + 524288;        // 524288 } V0,V1,V2 contiguous (917504)
  float* V1    = V0 + 524288;           // 262144 }
  float* V2    = V1 + 262144;           // 131072 }
  ushort* w1b  = (ushort*)(V2 + 131072);        // 2097152 ushort
  ushort* w2b  = w1b + 2097152;                 // 524288 ushort
  ushort* sp0a = w2b + 524288;                  // 524288 ushort each
  ushort* sp0b = sp0a + 524288;
  ushort* sp1a = sp0b + 524288;                 // 262144 ushort each
  ushort* sp1b = sp1a + 262144;
  ushort* sp2a = sp1b + 262144;                 // 131072 ushort each
  ushort* sp2b = sp2a + 131072;

  init_kernel<<<3584, 256, 0, stream>>>(V0, cost, tot);
  wnorm_kernel<<<3584, 64, 0, stream>>>(w0, w1, w2, wn);
  convert_w_kernel<<<1280, 256, 0, stream>>>(w1, w2, w1b, w2b);
  base0_mfma_kernel<<<dim3(4, 32), 256, 0, stream>>>(inputs, w0, base0);

  for (int d = 0; d <= 17; ++d) {
    step_kernel<<<224, 256, 0, stream>>>(
        base0, cn0, tn0, th0, wn, V0, sp0a, sp0b,
        w1b, cn1, tn1, th1, wn + 2048, V1, sp1a, sp1b,
        w2b, cn2, tn2, th2, wn + 3072, V2, sp2a, sp2b,
        out, cost, tot, d);
  }
  // layer-2 step-16 spikes live in sp2[16&1] = sp2a
  writeout_kernel<<<512, 256, 0, stream>>>(sp2a, out);
  finalize_kernel<<<1, 64, 0, stream>>>(cost, tot, out);
}